// Round 18
// baseline (85.382 us; speedup 1.0000x reference)
//
#include <hip/hip_runtime.h>
#include <hip/hip_bf16.h>

#define BI 2
#define NPOS 2304
#define HIDC 256
#define NH 8
#define HDIM 32
// scale folded into Wq/bq: S' = S_raw * SCALE * log2(e); P = 2^(S' - 32) via
// MFMA C-input = -32 (fixed-max softmax: the 2^-32 scale cancels in O/l).
#define QSCALE (0.17677669529663687f * 1.4426950408889634f)

typedef __attribute__((ext_vector_type(8))) short short8;
typedef __attribute__((ext_vector_type(4))) short short4v;
typedef __attribute__((ext_vector_type(4))) float f32x4;
typedef __attribute__((ext_vector_type(4))) float float4v;
typedef __attribute__((ext_vector_type(2))) unsigned uint2v;

__device__ inline short f2bf(float f) {
  union { float f; unsigned u; } v; v.f = f;
  unsigned u = v.u;
  unsigned r = (u + 0x7FFFu + ((u >> 16) & 1u)) >> 16;
  return (short)r;
}

__device__ inline float bf2f(short s) {
  union { unsigned u; float f; } v;
  v.u = ((unsigned)(unsigned short)s) << 16;
  return v.f;
}

__device__ inline float exp2_asm(float x) {
  float r; asm("v_exp_f32 %0, %1" : "=v"(r) : "v"(x)); return r;
}

__device__ inline unsigned pkbf(float a, float b) {
  __hip_bfloat162 h = __float22bfloat162_rn(make_float2(a, b));
  union { __hip_bfloat162 h; unsigned u; } cv; cv.h = h;
  return cv.u;
}

// ---------------------------------------------------------------------------
// Kernel A+B fused: one launch does both the X transpose-convert (y<24) and
// the weight conversions (y>=24). (unchanged from r17)
// ---------------------------------------------------------------------------
struct CvtArgs {
  const float* X1;
  const float* X2;
  short* X1t;
  short* X2t;
  const float* wsrc[8];
  short* wdst[8];
  int wnelem[8];
  float wscale[8];
};

__global__ __launch_bounds__(256) void convert_all(CvtArgs A) {
  const int y = blockIdx.y;
  const int tid = threadIdx.x;

  if (y < 24) {
    const int nb = blockIdx.x;
    if (nb >= 36) return;
    const float* X; short* Xt; int C, cb;
    if (y < 8) {
      int b = y >> 2; cb = y & 3; C = 256;
      X = A.X1 + (size_t)b * 256 * NPOS; Xt = A.X1t + (size_t)b * NPOS * 256;
    } else {
      int y2 = y - 8; int b = y2 >> 3; cb = y2 & 7; C = 512;
      X = A.X2 + (size_t)b * 512 * NPOS; Xt = A.X2t + (size_t)b * NPOS * 512;
    }
    const int c0 = cb * 64, n0 = nb * 64;
    __shared__ short T[64][68];
    const int col4 = (tid & 15) * 4, rowb = tid >> 4;
#pragma unroll
    for (int p = 0; p < 4; p++) {
      int row = p * 16 + rowb;
      float4v v = *(const float4v*)(X + (size_t)(c0 + row) * NPOS + n0 + col4);
      T[col4 + 0][row] = f2bf(v[0]);
      T[col4 + 1][row] = f2bf(v[1]);
      T[col4 + 2][row] = f2bf(v[2]);
      T[col4 + 3][row] = f2bf(v[3]);
    }
    __syncthreads();
#pragma unroll
    for (int p = 0; p < 2; p++) {
      int n = p * 32 + (tid >> 3), c8 = (tid & 7) * 8;
      short8 s = *(const short8*)&T[n][c8];
      *(short8*)(Xt + (size_t)(n0 + n) * C + c0 + c8) = s;
    }
  } else {
    const int seg = y - 24;
    const int idx = (blockIdx.x * 256 + tid) * 4;
    if (idx >= A.wnelem[seg]) return;
    const float sc = A.wscale[seg];
    const float4v v = *(const float4v*)(A.wsrc[seg] + idx);
    short4v s;
    s[0] = f2bf(v[0] * sc); s[1] = f2bf(v[1] * sc);
    s[2] = f2bf(v[2] * sc); s[3] = f2bf(v[3] * sc);
    *(short4v*)(A.wdst[seg] + idx) = s;
  }
}

// ---------------------------------------------------------------------------
// Kernel C: QKV projection GEMM (unchanged from r17).
// ---------------------------------------------------------------------------
__global__ __launch_bounds__(256) void proj_gemm(
    const short* Wc1, const short* Wc2, const short* X1t, const short* X2t,
    const float* bq1, const float* bk1, const float* bv1,
    const float* bq2, const float* bk2, const float* bv2,
    short* Q1t, short* K1t, short* V1, short* Q2t, short* K2t, short* V2) {
  const int nblk = blockIdx.x;   // 0..17
  const int mblk = blockIdx.y;   // 0..11
  const int z = blockIdx.z;      // 0..3
  const int b = z >> 1, modal = z & 1;
  const int K = modal ? 512 : 256;
  const short* Wp = modal ? Wc2 : Wc1;
  const short* Xp = (modal ? X2t : X1t) + (size_t)b * NPOS * K;
  const int m0 = mblk * 64, n0 = nblk * 128;
  const int seg = mblk >> 2;     // 0 Q, 1 K, 2 V

  __shared__ __attribute__((aligned(16))) short Al[64][72];
  __shared__ __attribute__((aligned(16))) short Bl[128][72];

  const int tid = threadIdx.x;
  const int lane = tid & 63;
  const int w = tid >> 6;
  const int q = lane & 15, g = lane >> 4;
  const int srow = tid >> 3, scol = (tid & 7) * 8;

  short8 ra[2], rb[4];
  auto loadt = [&](int kt) {
    ra[0] = *(const short8*)(Wp + (size_t)(m0 + srow) * K + kt + scol);
    ra[1] = *(const short8*)(Wp + (size_t)(m0 + 32 + srow) * K + kt + scol);
#pragma unroll
    for (int u = 0; u < 4; u++)
      rb[u] = *(const short8*)(Xp + (size_t)(n0 + u * 32 + srow) * K + kt + scol);
  };

  loadt(0);
  f32x4 acc[4][2];
#pragma unroll
  for (int i = 0; i < 4; i++)
#pragma unroll
    for (int j = 0; j < 2; j++)
      acc[i][j] = (f32x4){0.f, 0.f, 0.f, 0.f};

  const int NT = K / 64;
  for (int t = 0; t < NT; t++) {
    *(short8*)&Al[srow][scol] = ra[0];
    *(short8*)&Al[32 + srow][scol] = ra[1];
#pragma unroll
    for (int u = 0; u < 4; u++)
      *(short8*)&Bl[u * 32 + srow][scol] = rb[u];
    __syncthreads();
    if (t + 1 < NT) loadt((t + 1) * 64);
#pragma unroll
    for (int kk = 0; kk < 2; kk++) {
      short8 af[4], bfj[2];
#pragma unroll
      for (int i = 0; i < 4; i++)
        af[i] = *(const short8*)&Al[i * 16 + q][kk * 32 + g * 8];
#pragma unroll
      for (int j = 0; j < 2; j++)
        bfj[j] = *(const short8*)&Bl[w * 32 + j * 16 + q][kk * 32 + g * 8];
#pragma unroll
      for (int i = 0; i < 4; i++)
#pragma unroll
        for (int j = 0; j < 2; j++)
          acc[i][j] = __builtin_amdgcn_mfma_f32_16x16x32_bf16(af[i], bfj[j], acc[i][j], 0, 0, 0);
    }
    __syncthreads();
  }

  const float* bp = (seg == 0) ? (modal ? bq2 : bq1)
                  : (seg == 1) ? (modal ? bk2 : bk1)
                               : (modal ? bv2 : bv1);
  const float bscale = (seg == 0) ? (float)QSCALE : 1.0f;

  if (seg < 2) {
    short* outp = (seg == 0) ? (modal ? Q2t : Q1t) : (modal ? K2t : K1t);
#pragma unroll
    for (int i = 0; i < 4; i++) {
      int c0 = (m0 & 255) + i * 16 + g * 4;
      int h = c0 >> 5, d0 = c0 & 31;
      short* op = outp + (size_t)(b * NH + h) * NPOS * HDIM;
      float bb[4];
#pragma unroll
      for (int r = 0; r < 4; r++) bb[r] = bp[c0 + r] * bscale;
#pragma unroll
      for (int j = 0; j < 2; j++) {
        int n = n0 + w * 32 + j * 16 + q;
        short4v s;
#pragma unroll
        for (int r = 0; r < 4; r++) s[r] = f2bf(acc[i][j][r] + bb[r]);
        *(short4v*)&op[(size_t)n * HDIM + d0] = s;
      }
    }
  } else {
    short* outp = (modal ? V2 : V1) + (size_t)b * HIDC * NPOS;
#pragma unroll
    for (int i = 0; i < 4; i++) {
      int c0 = (m0 & 255) + i * 16 + g * 4;
#pragma unroll
      for (int j = 0; j < 2; j++) {
        int n = n0 + w * 32 + j * 16 + q;
#pragma unroll
        for (int r = 0; r < 4; r++)
          outp[(size_t)(c0 + r) * NPOS + n] = f2bf(acc[i][j][r] + bp[c0 + r]);
      }
    }
  }
}

// ---------------------------------------------------------------------------
// Kernel D: flash cross-attention — r16/r17 structure with ONE change: T5
// s_setprio(1) wrapped around the MFMA clusters (QK quad + PV sextet) so
// MFMA-entering waves preempt load/VALU-issuing waves from other co-resident
// blocks (cross-block phase skew provides the role diversity).
// ---------------------------------------------------------------------------
__global__ __launch_bounds__(256) void attn_kernel(
    const short* Q1t, const short* K1t, const short* V1,
    const short* Q2t, const short* K2t, const short* V2,
    short* Opart, float* Lpart) {
  // bijective XCD swizzle: 1728 = 8 XCDs x 216 (= 32 zh x 54 sub)
  const int id = blockIdx.x;
  const int nid = (id & 7) * 216 + (id >> 3);
  const int sub = nid % 54;
  const int ks = sub % 3;             // 0..2
  const int wt = sub / 3;             // 0..17 (128-query tiles)
  const int zh = nid / 54;            // 0..31
  const int h = zh & 7;
  const int z = zh >> 3;              // 0..3
  const int b = z >> 1, dir = z & 1;

  const short* Qp = (dir ? Q2t : Q1t) + (size_t)(b * NH + h) * NPOS * HDIM;
  const short* Kp = (dir ? K1t : K2t) + (size_t)(b * NH + h) * NPOS * HDIM;
  const short* Vp = (dir ? V1 : V2) + (size_t)b * HIDC * NPOS + (size_t)h * HDIM * NPOS;

  __shared__ __attribute__((aligned(16))) short Kl[2][64][40];
  __shared__ __attribute__((aligned(16))) short Vl[2][32][72];

  const int tid = threadIdx.x;
  const int lane = tid & 63;
  const int q = lane & 15, g = lane >> 4;
  const int w = tid >> 6;
  const int q0a = wt * 128 + w * 16;
  const int q0b = q0a + 64;
  const int k0 = ks * 768;

  const short8 qfa = *(const short8*)(Qp + (size_t)(q0a + q) * HDIM + g * 8);
  const short8 qfb = *(const short8*)(Qp + (size_t)(q0b + q) * HDIM + g * 8);

  // K staging: key kk = tid>>2 goes to permuted LDS row so that QK^T output
  // P-slots come out V-contiguous. kk = 32h + 8gg + 4ff + rr ->
  // row = (2h+ff)*16 + gg*4 + rr.
  const int kk_ = tid >> 2, kcol = (tid & 3) * 8;
  const int kperm = ((kk_ >> 5) * 2 + ((kk_ >> 2) & 1)) * 16
                  + ((kk_ >> 3) & 3) * 4 + (kk_ & 3);
  const int vrow = tid >> 3, vcol = (tid & 7) * 8;
  const short* Vrow = Vp + (size_t)vrow * NPOS;

  {
    short8 sk = *(const short8*)(Kp + k0 * 32 + tid * 8);
    short8 sv = *(const short8*)(Vrow + k0 + vcol);
    *(short8*)&Kl[0][kperm][kcol] = sk;
    *(short8*)&Vl[0][vrow][vcol] = sv;
  }
  __syncthreads();

  short8 ones;
#pragma unroll
  for (int i = 0; i < 8; i++) ones[i] = (short)0x3F80;  // bf16 1.0

  const f32x4 mC = {-32.f, -32.f, -32.f, -32.f};  // fixed-max fold
  const f32x4 fz = {0.f, 0.f, 0.f, 0.f};
  f32x4 accA0 = fz, accA1 = fz, acc2A = fz;
  f32x4 accB0 = fz, accB1 = fz, acc2B = fz;
  int cur = 0;

  for (int t = 0; t < 12; t++) {
    const int ktn = k0 + ((t < 11) ? (t + 1) * 64 : 0);
    short8 sk = *(const short8*)(Kp + ktn * 32 + tid * 8);
    short8 sv = *(const short8*)(Vrow + ktn + vcol);

    short8 kfr[4];
#pragma unroll
    for (int f = 0; f < 4; f++)
      kfr[f] = *(const short8*)&Kl[cur][f * 16 + q][g * 8];

    // V A-frags: plain contiguous b128 (keys mc*32 + g*8 .. +7), matching
    // the permuted P slot order. Query-independent, shared by both q-groups.
    short8 va[2][2];
#pragma unroll
    for (int dc = 0; dc < 2; dc++)
#pragma unroll
      for (int mc = 0; mc < 2; mc++)
        va[dc][mc] = *(const short8*)&Vl[cur][dc * 16 + q][mc * 32 + g * 8];

    // ---- q-group A ----
    {
      f32x4 sT[4];
      __builtin_amdgcn_s_setprio(1);
#pragma unroll
      for (int f = 0; f < 4; f++)
        sT[f] = __builtin_amdgcn_mfma_f32_16x16x32_bf16(kfr[f], qfa, mC, 0, 0, 0);
      __builtin_amdgcn_s_setprio(0);
#pragma unroll
      for (int f = 0; f < 4; f++)
#pragma unroll
        for (int r = 0; r < 4; r++)
          sT[f][r] = exp2_asm(sT[f][r]);
      union { unsigned u[4]; short8 s; } pb0, pb1;
      pb0.u[0] = pkbf(sT[0][0], sT[0][1]); pb0.u[1] = pkbf(sT[0][2], sT[0][3]);
      pb0.u[2] = pkbf(sT[1][0], sT[1][1]); pb0.u[3] = pkbf(sT[1][2], sT[1][3]);
      pb1.u[0] = pkbf(sT[2][0], sT[2][1]); pb1.u[1] = pkbf(sT[2][2], sT[2][3]);
      pb1.u[2] = pkbf(sT[3][0], sT[3][1]); pb1.u[3] = pkbf(sT[3][2], sT[3][3]);
      __builtin_amdgcn_s_setprio(1);
      accA0 = __builtin_amdgcn_mfma_f32_16x16x32_bf16(va[0][0], pb0.s, accA0, 0, 0, 0);
      accA1 = __builtin_amdgcn_mfma_f32_16x16x32_bf16(va[1][0], pb0.s, accA1, 0, 0, 0);
      acc2A = __builtin_amdgcn_mfma_f32_16x16x32_bf16(ones, pb0.s, acc2A, 0, 0, 0);
      accA0 = __builtin_amdgcn_mfma_f32_16x16x32_bf16(va[0][1], pb1.s, accA0, 0, 0, 0);
      accA1 = __builtin_amdgcn_mfma_f32_16x16x32_bf16(va[1][1], pb1.s, accA1, 0, 0, 0);
      acc2A = __builtin_amdgcn_mfma_f32_16x16x32_bf16(ones, pb1.s, acc2A, 0, 0, 0);
      __builtin_amdgcn_s_setprio(0);
    }
    // ---- q-group B (reuses kfr/va) ----
    {
      f32x4 sT[4];
      __builtin_amdgcn_s_setprio(1);
#pragma unroll
      for (int f = 0; f < 4; f++)
        sT[f] = __builtin_amdgcn_mfma_f32_16x16x32_bf16(kfr[f], qfb, mC, 0, 0, 0);
      __builtin_amdgcn_s_setprio(0);
#pragma unroll
      for (int f = 0; f < 4; f++)
#pragma unroll
        for (int r = 0; r < 4; r++)
          sT[f][r] = exp2_asm(sT[f][r]);
      union { unsigned u[4]; short8 s; } pb0, pb1;
      pb0.u[0] = pkbf(sT[0][0], sT[0][1]); pb0.u[1] = pkbf(sT[0][2], sT[0][3]);
      pb0.u[2] = pkbf(sT[1][0], sT[1][1]); pb0.u[3] = pkbf(sT[1][2], sT[1][3]);
      pb1.u[0] = pkbf(sT[2][0], sT[2][1]); pb1.u[1] = pkbf(sT[2][2], sT[2][3]);
      pb1.u[2] = pkbf(sT[3][0], sT[3][1]); pb1.u[3] = pkbf(sT[3][2], sT[3][3]);
      __builtin_amdgcn_s_setprio(1);
      accB0 = __builtin_amdgcn_mfma_f32_16x16x32_bf16(va[0][0], pb0.s, accB0, 0, 0, 0);
      accB1 = __builtin_amdgcn_mfma_f32_16x16x32_bf16(va[1][0], pb0.s, accB1, 0, 0, 0);
      acc2B = __builtin_amdgcn_mfma_f32_16x16x32_bf16(ones, pb0.s, acc2B, 0, 0, 0);
      accB0 = __builtin_amdgcn_mfma_f32_16x16x32_bf16(va[0][1], pb1.s, accB0, 0, 0, 0);
      accB1 = __builtin_amdgcn_mfma_f32_16x16x32_bf16(va[1][1], pb1.s, accB1, 0, 0, 0);
      acc2B = __builtin_amdgcn_mfma_f32_16x16x32_bf16(ones, pb1.s, acc2B, 0, 0, 0);
      __builtin_amdgcn_s_setprio(0);
    }

    *(short8*)&Kl[cur ^ 1][kperm][kcol] = sk;
    *(short8*)&Vl[cur ^ 1][vrow][vcol] = sv;
    __syncthreads();
    cur ^= 1;
  }

  const float lrA = acc2A[0];
  const float lrB = acc2B[0];

  // unnormalized partials: Opart[ks][zh][d 32][n 2304] bf16, Lpart[ks][zh][n]
  const size_t PH = (size_t)32 * 32 * NPOS;
  short* Pp = Opart + (size_t)ks * PH + (size_t)zh * 32 * NPOS;
#pragma unroll
  for (int r = 0; r < 4; r++) {
    Pp[(size_t)(g * 4 + r) * NPOS + q0a + q] = f2bf(accA0[r]);
    Pp[(size_t)(16 + g * 4 + r) * NPOS + q0a + q] = f2bf(accA1[r]);
    Pp[(size_t)(g * 4 + r) * NPOS + q0b + q] = f2bf(accB0[r]);
    Pp[(size_t)(16 + g * 4 + r) * NPOS + q0b + q] = f2bf(accB1[r]);
  }
  if (g == 0) {
    float* Lp = Lpart + (size_t)ks * (32 * NPOS) + (size_t)zh * NPOS;
    Lp[q0a + q] = lrA;
    Lp[q0b + q] = lrB;
  }
}

// ---------------------------------------------------------------------------
// Kernel D2: merge 3-way K-split partials, normalize, transpose to On n-major.
// (unchanged from r17)
// ---------------------------------------------------------------------------
__global__ __launch_bounds__(256) void merge_kernel(
    const short* Opart, const float* Lpart, short* On1, short* On2) {
  const int nt = blockIdx.x;
  const int zh = blockIdx.y;
  const int z = zh >> 3, h = zh & 7;
  const int b = z >> 1, dir = z & 1;
  const int n0 = nt * 64;
  const size_t PH = (size_t)32 * 32 * NPOS;
  const short* P0 = Opart + (size_t)zh * 32 * NPOS;
  const short* P1 = P0 + PH;
  const short* P2 = P0 + 2 * PH;
  const float* L0 = Lpart + (size_t)zh * NPOS;
  const float* L1 = L0 + (size_t)32 * NPOS;
  const float* L2 = L0 + (size_t)64 * NPOS;
  short* On = (dir ? On2 : On1) + (size_t)b * NPOS * HIDC;

  __shared__ float rl[64];
  __shared__ short T[64][36];

  const int tid = threadIdx.x;
  if (tid < 64) rl[tid] = 1.0f / (L0[n0 + tid] + L1[n0 + tid] + L2[n0 + tid]);
  __syncthreads();

  const int d = tid >> 3, nc = (tid & 7) * 8;
  short8 a = *(const short8*)(P0 + (size_t)d * NPOS + n0 + nc);
  short8 c = *(const short8*)(P1 + (size_t)d * NPOS + n0 + nc);
  short8 e = *(const short8*)(P2 + (size_t)d * NPOS + n0 + nc);
#pragma unroll
  for (int j = 0; j < 8; j++)
    T[nc + j][d] = f2bf((bf2f(a[j]) + bf2f(c[j]) + bf2f(e[j])) * rl[nc + j]);
  __syncthreads();

  const int n = tid >> 2, c8 = (tid & 3) * 8;
  short8 o = *(const short8*)&T[n][c8];
  *(short8*)(On + (size_t)(n0 + n) * HIDC + h * HDIM + c8) = o;
}

// ---------------------------------------------------------------------------
// Kernel E: output projection GEMM (unchanged from r17).
// ---------------------------------------------------------------------------
__global__ __launch_bounds__(256) void outproj_kernel(
    const short* Wo1b, const short* Wo2b, const float* bo1, const float* bo2,
    const short* On1, const short* On2, float* out) {
  const int nblk = blockIdx.x;
  const int mblk = blockIdx.y;
  const int z = blockIdx.z;
  const int dir = z >> 1, b = z & 1;
  const short* Wp = dir ? Wo2b : Wo1b;
  const float* bp = dir ? bo2 : bo1;
  const short* Xp = (dir ? On2 : On1) + (size_t)b * NPOS * HIDC;
  float* op = out + (size_t)dir * BI * HIDC * NPOS + (size_t)b * HIDC * NPOS;
  const int m0 = mblk * 64, n0 = nblk * 128;

  __shared__ __attribute__((aligned(16))) short Al[64][72];
  __shared__ __attribute__((aligned(16))) short Bl[128][72];

  const int tid = threadIdx.x;
  const int lane = tid & 63;
  const int w = tid >> 6;
  const int q = lane & 15, g = lane >> 4;
  const int srow = tid >> 3, scol = (tid & 7) * 8;

  short8 ra[2], rb[4];
  auto loadt = [&](int kt) {
    ra[0] = *(const short8*)(Wp + (size_t)(m0 + srow) * HIDC + kt + scol);
    ra[1] = *(const short8*)(Wp + (size_t)(m0 + 32 + srow) * HIDC + kt + scol);
#pragma unroll
    for (int u = 0; u < 4; u++)
      rb[u] = *(const short8*)(Xp + (size_t)(n0 + u * 32 + srow) * HIDC + kt + scol);
  };

  loadt(0);
  f32x4 acc[4][2];
#pragma unroll
  for (int i = 0; i < 4; i++)
#pragma unroll
    for (int j = 0; j < 2; j++)
      acc[i][j] = (f32x4){0.f, 0.f, 0.f, 0.f};

  for (int t = 0; t < 4; t++) {
    *(short8*)&Al[srow][scol] = ra[0];
    *(short8*)&Al[32 + srow][scol] = ra[1];
#pragma unroll
    for (int u = 0; u < 4; u++)
      *(short8*)&Bl[u * 32 + srow][scol] = rb[u];
    __syncthreads();
    if (t + 1 < 4) loadt((t + 1) * 64);
#pragma unroll
    for (int kk = 0; kk < 2; kk++) {
      short8 af[4], bfj[2];
#pragma unroll
      for (int i = 0; i < 4; i++)
        af[i] = *(const short8*)&Al[i * 16 + q][kk * 32 + g * 8];
#pragma unroll
      for (int j = 0; j < 2; j++)
        bfj[j] = *(const short8*)&Bl[w * 32 + j * 16 + q][kk * 32 + g * 8];
#pragma unroll
      for (int i = 0; i < 4; i++)
#pragma unroll
        for (int j = 0; j < 2; j++)
          acc[i][j] = __builtin_amdgcn_mfma_f32_16x16x32_bf16(af[i], bfj[j], acc[i][j], 0, 0, 0);
    }
    __syncthreads();
  }

#pragma unroll
  for (int i = 0; i < 4; i++) {
    int c0 = m0 + i * 16 + g * 4;
#pragma unroll
    for (int r = 0; r < 4; r++) {
      float bb = bp[c0 + r];
#pragma unroll
      for (int j = 0; j < 2; j++) {
        int n = n0 + w * 32 + j * 16 + q;
        op[(size_t)(c0 + r) * NPOS + n] = acc[i][j][r] + bb;
      }
    }
  }
}

// ---------------------------------------------------------------------------
// ws layout (SZ = 1,179,648 elems = 2.36 MB; peak ~30 MB, proven fit):
//  0..6  SZ: Q1t,K1t,V1,Q2t,K2t,V2      (dead after attn)
//  6..9  SZ: X1t,X2t                    (dead after proj_gemm)
//  6..12 SZ: Opart [3ks][32zh][32d][2304n] bf16 (overlays X)
// 12 SZ+   : Lpart [3ks][32zh][2304n] f32, then Wc1, Wc2, Wo1b, Wo2b
//  0..2  SZ: On1, On2 (overlay Q1t/K1t after attn)
// ---------------------------------------------------------------------------
extern "C" void kernel_launch(void* const* d_in, const int* in_sizes, int n_in,
                              void* d_out, int out_size, void* d_ws, size_t ws_size,
                              hipStream_t stream) {
  const float* m1 = (const float*)d_in[0];
  const float* m2 = (const float*)d_in[1];

  const size_t SZ = (size_t)BI * HIDC * NPOS;  // 1,179,648 elements
  short* ws = (short*)d_ws;
  short* Q1t = ws + 0 * SZ;
  short* K1t = ws + 1 * SZ;
  short* V1  = ws + 2 * SZ;
  short* Q2t = ws + 3 * SZ;
  short* K2t = ws + 4 * SZ;
  short* V2  = ws + 5 * SZ;
  short* X1t = ws + 6 * SZ;                    // 1 SZ
  short* X2t = ws + 7 * SZ;                    // 2 SZ
  short* Opart = ws + 6 * SZ;                  // 6 SZ (overlays X)
  float* Lpart = (float*)(ws + 12 * SZ);       // 3*32*2304 f32 = 884,736 B
  short* On1 = ws + 0 * SZ;                    // overlays Q1t (dead after attn)
  short* On2 = ws + 1 * SZ;                    // overlays K1t
  short* Wc1 = ws + 12 * SZ + 442368;          // after Lpart
  short* Wc2 = Wc1 + 768 * 256;
  short* Wo1b = Wc2 + 768 * 512;
  short* Wo2b = Wo1b + 256 * 256;

  // A+B fused: X transpose-convert + weight conversions in one launch
  CvtArgs CA;
  CA.X1 = m1; CA.X2 = m2; CA.X1t = X1t; CA.X2t = X2t;
  CA.wsrc[0] = (const float*)d_in[2];  CA.wdst[0] = Wc1;          CA.wnelem[0] = 65536;  CA.wscale[0] = (float)QSCALE;
  CA.wsrc[1] = (const float*)d_in[4];  CA.wdst[1] = Wc1 + 65536;  CA.wnelem[1] = 65536;  CA.wscale[1] = 1.f;
  CA.wsrc[2] = (const float*)d_in[6];  CA.wdst[2] = Wc1 + 131072; CA.wnelem[2] = 65536;  CA.wscale[2] = 1.f;
  CA.wsrc[3] = (const float*)d_in[8];  CA.wdst[3] = Wc2;          CA.wnelem[3] = 131072; CA.wscale[3] = (float)QSCALE;
  CA.wsrc[4] = (const float*)d_in[10]; CA.wdst[4] = Wc2 + 131072; CA.wnelem[4] = 131072; CA.wscale[4] = 1.f;
  CA.wsrc[5] = (const float*)d_in[12]; CA.wdst[5] = Wc2 + 262144; CA.wnelem[5] = 131072; CA.wscale[5] = 1.f;
  CA.wsrc[6] = (const float*)d_in[14]; CA.wdst[6] = Wo1b;         CA.wnelem[6] = 65536;  CA.wscale[6] = 1.f;
  CA.wsrc[7] = (const float*)d_in[16]; CA.wdst[7] = Wo2b;         CA.wnelem[7] = 65536;  CA.wscale[7] = 1.f;
  hipLaunchKernelGGL(convert_all, dim3(128, 32), dim3(256), 0, stream, CA);

  // C: QKV projection GEMM
  hipLaunchKernelGGL(proj_gemm, dim3(18, 12, 4), dim3(256), 0, stream,
                     Wc1, Wc2, X1t, X2t,
                     (const float*)d_in[3], (const float*)d_in[5], (const float*)d_in[7],
                     (const float*)d_in[9], (const float*)d_in[11], (const float*)d_in[13],
                     Q1t, K1t, V1, Q2t, K2t, V2);

  // D: attention (3-way K-split; 128 queries/block; permuted-K staging; T5)
  hipLaunchKernelGGL(attn_kernel, dim3(1728), dim3(256), 0, stream,
                     Q1t, K1t, V1, Q2t, K2t, V2, Opart, Lpart);

  // D2: merge + normalize + transpose
  hipLaunchKernelGGL(merge_kernel, dim3(36, 32), dim3(256), 0, stream,
                     Opart, Lpart, On1, On2);

  // E: output projection GEMM
  hipLaunchKernelGGL(outproj_kernel, dim3(18, 4, 4), dim3(256), 0, stream,
                     Wo1b, Wo2b, (const float*)d_in[15], (const float*)d_in[17],
                     On1, On2, (float*)d_out);
}

// Round 19
// 81.457 us; speedup vs baseline: 1.0482x; 1.0482x over previous
//
#include <hip/hip_runtime.h>
#include <hip/hip_bf16.h>

#define BI 2
#define NPOS 2304
#define HIDC 256
#define NH 8
#define HDIM 32
// scale folded into Wq/bq: S' = S_raw * SCALE * log2(e); P = 2^(S' - 32) via
// MFMA C-input = -32 (fixed-max softmax: the 2^-32 scale cancels in O/l).
#define QSCALE (0.17677669529663687f * 1.4426950408889634f)

typedef __attribute__((ext_vector_type(8))) short short8;
typedef __attribute__((ext_vector_type(4))) short short4v;
typedef __attribute__((ext_vector_type(4))) float f32x4;
typedef __attribute__((ext_vector_type(4))) float float4v;
typedef __attribute__((ext_vector_type(2))) unsigned uint2v;

__device__ inline short f2bf(float f) {
  union { float f; unsigned u; } v; v.f = f;
  unsigned u = v.u;
  unsigned r = (u + 0x7FFFu + ((u >> 16) & 1u)) >> 16;
  return (short)r;
}

__device__ inline float bf2f(short s) {
  union { unsigned u; float f; } v;
  v.u = ((unsigned)(unsigned short)s) << 16;
  return v.f;
}

__device__ inline float exp2_asm(float x) {
  float r; asm("v_exp_f32 %0, %1" : "=v"(r) : "v"(x)); return r;
}

__device__ inline unsigned pkbf(float a, float b) {
  __hip_bfloat162 h = __float22bfloat162_rn(make_float2(a, b));
  union { __hip_bfloat162 h; unsigned u; } cv; cv.h = h;
  return cv.u;
}

// ---------------------------------------------------------------------------
// Kernel A+B fused: one launch does both the X transpose-convert (y<24) and
// the weight conversions (y>=24). Work is independent & disjoint; off-range
// blocks exit immediately.
// ---------------------------------------------------------------------------
struct CvtArgs {
  const float* X1;
  const float* X2;
  short* X1t;
  short* X2t;
  const float* wsrc[8];
  short* wdst[8];
  int wnelem[8];
  float wscale[8];
};

__global__ __launch_bounds__(256) void convert_all(CvtArgs A) {
  const int y = blockIdx.y;
  const int tid = threadIdx.x;

  if (y < 24) {
    // ---- X transpose-convert: f32 [b][C][N] -> bf16 [b][N][C] ----
    const int nb = blockIdx.x;
    if (nb >= 36) return;
    const float* X; short* Xt; int C, cb;
    if (y < 8) {
      int b = y >> 2; cb = y & 3; C = 256;
      X = A.X1 + (size_t)b * 256 * NPOS; Xt = A.X1t + (size_t)b * NPOS * 256;
    } else {
      int y2 = y - 8; int b = y2 >> 3; cb = y2 & 7; C = 512;
      X = A.X2 + (size_t)b * 512 * NPOS; Xt = A.X2t + (size_t)b * NPOS * 512;
    }
    const int c0 = cb * 64, n0 = nb * 64;
    __shared__ short T[64][68];
    const int col4 = (tid & 15) * 4, rowb = tid >> 4;
#pragma unroll
    for (int p = 0; p < 4; p++) {
      int row = p * 16 + rowb;
      float4v v = *(const float4v*)(X + (size_t)(c0 + row) * NPOS + n0 + col4);
      T[col4 + 0][row] = f2bf(v[0]);
      T[col4 + 1][row] = f2bf(v[1]);
      T[col4 + 2][row] = f2bf(v[2]);
      T[col4 + 3][row] = f2bf(v[3]);
    }
    __syncthreads();
#pragma unroll
    for (int p = 0; p < 2; p++) {
      int n = p * 32 + (tid >> 3), c8 = (tid & 7) * 8;
      short8 s = *(const short8*)&T[n][c8];
      *(short8*)(Xt + (size_t)(n0 + n) * C + c0 + c8) = s;
    }
  } else {
    // ---- weight conversion (stacked; QSCALE folded into Wq) ----
    const int seg = y - 24;
    const int idx = (blockIdx.x * 256 + tid) * 4;
    if (idx >= A.wnelem[seg]) return;
    const float sc = A.wscale[seg];
    const float4v v = *(const float4v*)(A.wsrc[seg] + idx);
    short4v s;
    s[0] = f2bf(v[0] * sc); s[1] = f2bf(v[1] * sc);
    s[2] = f2bf(v[2] * sc); s[3] = f2bf(v[3] * sc);
    *(short4v*)(A.wdst[seg] + idx) = s;
  }
}

// ---------------------------------------------------------------------------
// Kernel C: QKV projection GEMM (r12 structure, unchanged).
// ---------------------------------------------------------------------------
__global__ __launch_bounds__(256) void proj_gemm(
    const short* Wc1, const short* Wc2, const short* X1t, const short* X2t,
    const float* bq1, const float* bk1, const float* bv1,
    const float* bq2, const float* bk2, const float* bv2,
    short* Q1t, short* K1t, short* V1, short* Q2t, short* K2t, short* V2) {
  const int nblk = blockIdx.x;   // 0..17
  const int mblk = blockIdx.y;   // 0..11
  const int z = blockIdx.z;      // 0..3
  const int b = z >> 1, modal = z & 1;
  const int K = modal ? 512 : 256;
  const short* Wp = modal ? Wc2 : Wc1;
  const short* Xp = (modal ? X2t : X1t) + (size_t)b * NPOS * K;
  const int m0 = mblk * 64, n0 = nblk * 128;
  const int seg = mblk >> 2;     // 0 Q, 1 K, 2 V

  __shared__ __attribute__((aligned(16))) short Al[64][72];
  __shared__ __attribute__((aligned(16))) short Bl[128][72];

  const int tid = threadIdx.x;
  const int lane = tid & 63;
  const int w = tid >> 6;
  const int q = lane & 15, g = lane >> 4;
  const int srow = tid >> 3, scol = (tid & 7) * 8;

  short8 ra[2], rb[4];
  auto loadt = [&](int kt) {
    ra[0] = *(const short8*)(Wp + (size_t)(m0 + srow) * K + kt + scol);
    ra[1] = *(const short8*)(Wp + (size_t)(m0 + 32 + srow) * K + kt + scol);
#pragma unroll
    for (int u = 0; u < 4; u++)
      rb[u] = *(const short8*)(Xp + (size_t)(n0 + u * 32 + srow) * K + kt + scol);
  };

  loadt(0);
  f32x4 acc[4][2];
#pragma unroll
  for (int i = 0; i < 4; i++)
#pragma unroll
    for (int j = 0; j < 2; j++)
      acc[i][j] = (f32x4){0.f, 0.f, 0.f, 0.f};

  const int NT = K / 64;
  for (int t = 0; t < NT; t++) {
    *(short8*)&Al[srow][scol] = ra[0];
    *(short8*)&Al[32 + srow][scol] = ra[1];
#pragma unroll
    for (int u = 0; u < 4; u++)
      *(short8*)&Bl[u * 32 + srow][scol] = rb[u];
    __syncthreads();
    if (t + 1 < NT) loadt((t + 1) * 64);
#pragma unroll
    for (int kk = 0; kk < 2; kk++) {
      short8 af[4], bfj[2];
#pragma unroll
      for (int i = 0; i < 4; i++)
        af[i] = *(const short8*)&Al[i * 16 + q][kk * 32 + g * 8];
#pragma unroll
      for (int j = 0; j < 2; j++)
        bfj[j] = *(const short8*)&Bl[w * 32 + j * 16 + q][kk * 32 + g * 8];
#pragma unroll
      for (int i = 0; i < 4; i++)
#pragma unroll
        for (int j = 0; j < 2; j++)
          acc[i][j] = __builtin_amdgcn_mfma_f32_16x16x32_bf16(af[i], bfj[j], acc[i][j], 0, 0, 0);
    }
    __syncthreads();
  }

  const float* bp = (seg == 0) ? (modal ? bq2 : bq1)
                  : (seg == 1) ? (modal ? bk2 : bk1)
                               : (modal ? bv2 : bv1);
  const float bscale = (seg == 0) ? (float)QSCALE : 1.0f;

  if (seg < 2) {
    short* outp = (seg == 0) ? (modal ? Q2t : Q1t) : (modal ? K2t : K1t);
#pragma unroll
    for (int i = 0; i < 4; i++) {
      int c0 = (m0 & 255) + i * 16 + g * 4;
      int h = c0 >> 5, d0 = c0 & 31;
      short* op = outp + (size_t)(b * NH + h) * NPOS * HDIM;
      float bb[4];
#pragma unroll
      for (int r = 0; r < 4; r++) bb[r] = bp[c0 + r] * bscale;
#pragma unroll
      for (int j = 0; j < 2; j++) {
        int n = n0 + w * 32 + j * 16 + q;
        short4v s;
#pragma unroll
        for (int r = 0; r < 4; r++) s[r] = f2bf(acc[i][j][r] + bb[r]);
        *(short4v*)&op[(size_t)n * HDIM + d0] = s;
      }
    }
  } else {
    short* outp = (modal ? V2 : V1) + (size_t)b * HIDC * NPOS;
#pragma unroll
    for (int i = 0; i < 4; i++) {
      int c0 = (m0 & 255) + i * 16 + g * 4;
#pragma unroll
      for (int j = 0; j < 2; j++) {
        int n = n0 + w * 32 + j * 16 + q;
#pragma unroll
        for (int r = 0; r < 4; r++)
          outp[(size_t)(c0 + r) * NPOS + n] = f2bf(acc[i][j][r] + bp[c0 + r]);
      }
    }
  }
}

// ---------------------------------------------------------------------------
// Kernel D: flash cross-attention (r16/r17 proven best — permuted-K staging,
// 128q/block, 2 q-groups, 3-way K-split, K+V LDS double-buffered,
// in-register P, contiguous b128 V A-frags; NO setprio).
// ---------------------------------------------------------------------------
__global__ __launch_bounds__(256) void attn_kernel(
    const short* Q1t, const short* K1t, const short* V1,
    const short* Q2t, const short* K2t, const short* V2,
    short* Opart, float* Lpart) {
  // bijective XCD swizzle: 1728 = 8 XCDs x 216 (= 32 zh x 54 sub)
  const int id = blockIdx.x;
  const int nid = (id & 7) * 216 + (id >> 3);
  const int sub = nid % 54;
  const int ks = sub % 3;             // 0..2
  const int wt = sub / 3;             // 0..17 (128-query tiles)
  const int zh = nid / 54;            // 0..31
  const int h = zh & 7;
  const int z = zh >> 3;              // 0..3
  const int b = z >> 1, dir = z & 1;

  const short* Qp = (dir ? Q2t : Q1t) + (size_t)(b * NH + h) * NPOS * HDIM;
  const short* Kp = (dir ? K1t : K2t) + (size_t)(b * NH + h) * NPOS * HDIM;
  const short* Vp = (dir ? V1 : V2) + (size_t)b * HIDC * NPOS + (size_t)h * HDIM * NPOS;

  __shared__ __attribute__((aligned(16))) short Kl[2][64][40];
  __shared__ __attribute__((aligned(16))) short Vl[2][32][72];

  const int tid = threadIdx.x;
  const int lane = tid & 63;
  const int q = lane & 15, g = lane >> 4;
  const int w = tid >> 6;
  const int q0a = wt * 128 + w * 16;
  const int q0b = q0a + 64;
  const int k0 = ks * 768;

  const short8 qfa = *(const short8*)(Qp + (size_t)(q0a + q) * HDIM + g * 8);
  const short8 qfb = *(const short8*)(Qp + (size_t)(q0b + q) * HDIM + g * 8);

  // K staging: key kk = tid>>2 goes to permuted LDS row so that QK^T output
  // P-slots come out V-contiguous. kk = 32h + 8gg + 4ff + rr ->
  // row = (2h+ff)*16 + gg*4 + rr.
  const int kk_ = tid >> 2, kcol = (tid & 3) * 8;
  const int kperm = ((kk_ >> 5) * 2 + ((kk_ >> 2) & 1)) * 16
                  + ((kk_ >> 3) & 3) * 4 + (kk_ & 3);
  const int vrow = tid >> 3, vcol = (tid & 7) * 8;
  const short* Vrow = Vp + (size_t)vrow * NPOS;

  {
    short8 sk = *(const short8*)(Kp + k0 * 32 + tid * 8);
    short8 sv = *(const short8*)(Vrow + k0 + vcol);
    *(short8*)&Kl[0][kperm][kcol] = sk;
    *(short8*)&Vl[0][vrow][vcol] = sv;
  }
  __syncthreads();

  short8 ones;
#pragma unroll
  for (int i = 0; i < 8; i++) ones[i] = (short)0x3F80;  // bf16 1.0

  const f32x4 mC = {-32.f, -32.f, -32.f, -32.f};  // fixed-max fold
  const f32x4 fz = {0.f, 0.f, 0.f, 0.f};
  f32x4 accA0 = fz, accA1 = fz, acc2A = fz;
  f32x4 accB0 = fz, accB1 = fz, acc2B = fz;
  int cur = 0;

  for (int t = 0; t < 12; t++) {
    const int ktn = k0 + ((t < 11) ? (t + 1) * 64 : 0);
    short8 sk = *(const short8*)(Kp + ktn * 32 + tid * 8);
    short8 sv = *(const short8*)(Vrow + ktn + vcol);

    short8 kfr[4];
#pragma unroll
    for (int f = 0; f < 4; f++)
      kfr[f] = *(const short8*)&Kl[cur][f * 16 + q][g * 8];

    // V A-frags: plain contiguous b128 (keys mc*32 + g*8 .. +7), matching
    // the permuted P slot order. Query-independent, shared by both q-groups.
    short8 va[2][2];
#pragma unroll
    for (int dc = 0; dc < 2; dc++)
#pragma unroll
      for (int mc = 0; mc < 2; mc++)
        va[dc][mc] = *(const short8*)&Vl[cur][dc * 16 + q][mc * 32 + g * 8];

    // ---- q-group A ----
    {
      f32x4 sT[4];
#pragma unroll
      for (int f = 0; f < 4; f++)
        sT[f] = __builtin_amdgcn_mfma_f32_16x16x32_bf16(kfr[f], qfa, mC, 0, 0, 0);
#pragma unroll
      for (int f = 0; f < 4; f++)
#pragma unroll
        for (int r = 0; r < 4; r++)
          sT[f][r] = exp2_asm(sT[f][r]);
      union { unsigned u[4]; short8 s; } pb0, pb1;
      pb0.u[0] = pkbf(sT[0][0], sT[0][1]); pb0.u[1] = pkbf(sT[0][2], sT[0][3]);
      pb0.u[2] = pkbf(sT[1][0], sT[1][1]); pb0.u[3] = pkbf(sT[1][2], sT[1][3]);
      pb1.u[0] = pkbf(sT[2][0], sT[2][1]); pb1.u[1] = pkbf(sT[2][2], sT[2][3]);
      pb1.u[2] = pkbf(sT[3][0], sT[3][1]); pb1.u[3] = pkbf(sT[3][2], sT[3][3]);
      accA0 = __builtin_amdgcn_mfma_f32_16x16x32_bf16(va[0][0], pb0.s, accA0, 0, 0, 0);
      accA1 = __builtin_amdgcn_mfma_f32_16x16x32_bf16(va[1][0], pb0.s, accA1, 0, 0, 0);
      acc2A = __builtin_amdgcn_mfma_f32_16x16x32_bf16(ones, pb0.s, acc2A, 0, 0, 0);
      accA0 = __builtin_amdgcn_mfma_f32_16x16x32_bf16(va[0][1], pb1.s, accA0, 0, 0, 0);
      accA1 = __builtin_amdgcn_mfma_f32_16x16x32_bf16(va[1][1], pb1.s, accA1, 0, 0, 0);
      acc2A = __builtin_amdgcn_mfma_f32_16x16x32_bf16(ones, pb1.s, acc2A, 0, 0, 0);
    }
    // ---- q-group B (reuses kfr/va) ----
    {
      f32x4 sT[4];
#pragma unroll
      for (int f = 0; f < 4; f++)
        sT[f] = __builtin_amdgcn_mfma_f32_16x16x32_bf16(kfr[f], qfb, mC, 0, 0, 0);
#pragma unroll
      for (int f = 0; f < 4; f++)
#pragma unroll
        for (int r = 0; r < 4; r++)
          sT[f][r] = exp2_asm(sT[f][r]);
      union { unsigned u[4]; short8 s; } pb0, pb1;
      pb0.u[0] = pkbf(sT[0][0], sT[0][1]); pb0.u[1] = pkbf(sT[0][2], sT[0][3]);
      pb0.u[2] = pkbf(sT[1][0], sT[1][1]); pb0.u[3] = pkbf(sT[1][2], sT[1][3]);
      pb1.u[0] = pkbf(sT[2][0], sT[2][1]); pb1.u[1] = pkbf(sT[2][2], sT[2][3]);
      pb1.u[2] = pkbf(sT[3][0], sT[3][1]); pb1.u[3] = pkbf(sT[3][2], sT[3][3]);
      accB0 = __builtin_amdgcn_mfma_f32_16x16x32_bf16(va[0][0], pb0.s, accB0, 0, 0, 0);
      accB1 = __builtin_amdgcn_mfma_f32_16x16x32_bf16(va[1][0], pb0.s, accB1, 0, 0, 0);
      acc2B = __builtin_amdgcn_mfma_f32_16x16x32_bf16(ones, pb0.s, acc2B, 0, 0, 0);
      accB0 = __builtin_amdgcn_mfma_f32_16x16x32_bf16(va[0][1], pb1.s, accB0, 0, 0, 0);
      accB1 = __builtin_amdgcn_mfma_f32_16x16x32_bf16(va[1][1], pb1.s, accB1, 0, 0, 0);
      acc2B = __builtin_amdgcn_mfma_f32_16x16x32_bf16(ones, pb1.s, acc2B, 0, 0, 0);
    }

    *(short8*)&Kl[cur ^ 1][kperm][kcol] = sk;
    *(short8*)&Vl[cur ^ 1][vrow][vcol] = sv;
    __syncthreads();
    cur ^= 1;
  }

  const float lrA = acc2A[0];
  const float lrB = acc2B[0];

  // unnormalized partials: Opart[ks][zh][d 32][n 2304] bf16, Lpart[ks][zh][n]
  const size_t PH = (size_t)32 * 32 * NPOS;
  short* Pp = Opart + (size_t)ks * PH + (size_t)zh * 32 * NPOS;
#pragma unroll
  for (int r = 0; r < 4; r++) {
    Pp[(size_t)(g * 4 + r) * NPOS + q0a + q] = f2bf(accA0[r]);
    Pp[(size_t)(16 + g * 4 + r) * NPOS + q0a + q] = f2bf(accA1[r]);
    Pp[(size_t)(g * 4 + r) * NPOS + q0b + q] = f2bf(accB0[r]);
    Pp[(size_t)(16 + g * 4 + r) * NPOS + q0b + q] = f2bf(accB1[r]);
  }
  if (g == 0) {
    float* Lp = Lpart + (size_t)ks * (32 * NPOS) + (size_t)zh * NPOS;
    Lp[q0a + q] = lrA;
    Lp[q0b + q] = lrB;
  }
}

// ---------------------------------------------------------------------------
// Kernel D2: merge 3-way K-split partials, normalize, transpose to On n-major.
// ---------------------------------------------------------------------------
__global__ __launch_bounds__(256) void merge_kernel(
    const short* Opart, const float* Lpart, short* On1, short* On2) {
  const int nt = blockIdx.x;
  const int zh = blockIdx.y;
  const int z = zh >> 3, h = zh & 7;
  const int b = z >> 1, dir = z & 1;
  const int n0 = nt * 64;
  const size_t PH = (size_t)32 * 32 * NPOS;
  const short* P0 = Opart + (size_t)zh * 32 * NPOS;
  const short* P1 = P0 + PH;
  const short* P2 = P0 + 2 * PH;
  const float* L0 = Lpart + (size_t)zh * NPOS;
  const float* L1 = L0 + (size_t)32 * NPOS;
  const float* L2 = L0 + (size_t)64 * NPOS;
  short* On = (dir ? On2 : On1) + (size_t)b * NPOS * HIDC;

  __shared__ float rl[64];
  __shared__ short T[64][36];

  const int tid = threadIdx.x;
  if (tid < 64) rl[tid] = 1.0f / (L0[n0 + tid] + L1[n0 + tid] + L2[n0 + tid]);
  __syncthreads();

  const int d = tid >> 3, nc = (tid & 7) * 8;
  short8 a = *(const short8*)(P0 + (size_t)d * NPOS + n0 + nc);
  short8 c = *(const short8*)(P1 + (size_t)d * NPOS + n0 + nc);
  short8 e = *(const short8*)(P2 + (size_t)d * NPOS + n0 + nc);
#pragma unroll
  for (int j = 0; j < 8; j++)
    T[nc + j][d] = f2bf((bf2f(a[j]) + bf2f(c[j]) + bf2f(e[j])) * rl[nc + j]);
  __syncthreads();

  const int n = tid >> 2, c8 = (tid & 3) * 8;
  short8 o = *(const short8*)&T[n][c8];
  *(short8*)(On + (size_t)(n0 + n) * HIDC + h * HDIM + c8) = o;
}

// ---------------------------------------------------------------------------
// Kernel E: output projection GEMM.
// ---------------------------------------------------------------------------
__global__ __launch_bounds__(256) void outproj_kernel(
    const short* Wo1b, const short* Wo2b, const float* bo1, const float* bo2,
    const short* On1, const short* On2, float* out) {
  const int nblk = blockIdx.x;
  const int mblk = blockIdx.y;
  const int z = blockIdx.z;
  const int dir = z >> 1, b = z & 1;
  const short* Wp = dir ? Wo2b : Wo1b;
  const float* bp = dir ? bo2 : bo1;
  const short* Xp = (dir ? On2 : On1) + (size_t)b * NPOS * HIDC;
  float* op = out + (size_t)dir * BI * HIDC * NPOS + (size_t)b * HIDC * NPOS;
  const int m0 = mblk * 64, n0 = nblk * 128;

  __shared__ __attribute__((aligned(16))) short Al[64][72];
  __shared__ __attribute__((aligned(16))) short Bl[128][72];

  const int tid = threadIdx.x;
  const int lane = tid & 63;
  const int w = tid >> 6;
  const int q = lane & 15, g = lane >> 4;
  const int srow = tid >> 3, scol = (tid & 7) * 8;

  short8 ra[2], rb[4];
  auto loadt = [&](int kt) {
    ra[0] = *(const short8*)(Wp + (size_t)(m0 + srow) * HIDC + kt + scol);
    ra[1] = *(const short8*)(Wp + (size_t)(m0 + 32 + srow) * HIDC + kt + scol);
#pragma unroll
    for (int u = 0; u < 4; u++)
      rb[u] = *(const short8*)(Xp + (size_t)(n0 + u * 32 + srow) * HIDC + kt + scol);
  };

  loadt(0);
  f32x4 acc[4][2];
#pragma unroll
  for (int i = 0; i < 4; i++)
#pragma unroll
    for (int j = 0; j < 2; j++)
      acc[i][j] = (f32x4){0.f, 0.f, 0.f, 0.f};

  for (int t = 0; t < 4; t++) {
    *(short8*)&Al[srow][scol] = ra[0];
    *(short8*)&Al[32 + srow][scol] = ra[1];
#pragma unroll
    for (int u = 0; u < 4; u++)
      *(short8*)&Bl[u * 32 + srow][scol] = rb[u];
    __syncthreads();
    if (t + 1 < 4) loadt((t + 1) * 64);
#pragma unroll
    for (int kk = 0; kk < 2; kk++) {
      short8 af[4], bfj[2];
#pragma unroll
      for (int i = 0; i < 4; i++)
        af[i] = *(const short8*)&Al[i * 16 + q][kk * 32 + g * 8];
#pragma unroll
      for (int j = 0; j < 2; j++)
        bfj[j] = *(const short8*)&Bl[w * 32 + j * 16 + q][kk * 32 + g * 8];
#pragma unroll
      for (int i = 0; i < 4; i++)
#pragma unroll
        for (int j = 0; j < 2; j++)
          acc[i][j] = __builtin_amdgcn_mfma_f32_16x16x32_bf16(af[i], bfj[j], acc[i][j], 0, 0, 0);
    }
    __syncthreads();
  }

#pragma unroll
  for (int i = 0; i < 4; i++) {
    int c0 = m0 + i * 16 + g * 4;
#pragma unroll
    for (int r = 0; r < 4; r++) {
      float bb = bp[c0 + r];
#pragma unroll
      for (int j = 0; j < 2; j++) {
        int n = n0 + w * 32 + j * 16 + q;
        op[(size_t)(c0 + r) * NPOS + n] = acc[i][j][r] + bb;
      }
    }
  }
}

// ---------------------------------------------------------------------------
// ws layout (SZ = 1,179,648 elems = 2.36 MB; peak ~30 MB, proven fit):
//  0..6  SZ: Q1t,K1t,V1,Q2t,K2t,V2      (dead after attn)
//  6..9  SZ: X1t,X2t                    (dead after proj_gemm)
//  6..12 SZ: Opart [3ks][32zh][32d][2304n] bf16 (overlays X)
// 12 SZ+   : Lpart [3ks][32zh][2304n] f32, then Wc1, Wc2, Wo1b, Wo2b
//  0..2  SZ: On1, On2 (overlay Q1t/K1t after attn)
// ---------------------------------------------------------------------------
extern "C" void kernel_launch(void* const* d_in, const int* in_sizes, int n_in,
                              void* d_out, int out_size, void* d_ws, size_t ws_size,
                              hipStream_t stream) {
  const float* m1 = (const float*)d_in[0];
  const float* m2 = (const float*)d_in[1];

  const size_t SZ = (size_t)BI * HIDC * NPOS;  // 1,179,648 elements
  short* ws = (short*)d_ws;
  short* Q1t = ws + 0 * SZ;
  short* K1t = ws + 1 * SZ;
  short* V1  = ws + 2 * SZ;
  short* Q2t = ws + 3 * SZ;
  short* K2t = ws + 4 * SZ;
  short* V2  = ws + 5 * SZ;
  short* X1t = ws + 6 * SZ;                    // 1 SZ
  short* X2t = ws + 7 * SZ;                    // 2 SZ
  short* Opart = ws + 6 * SZ;                  // 6 SZ (overlays X)
  float* Lpart = (float*)(ws + 12 * SZ);       // 3*32*2304 f32 = 884,736 B
  short* On1 = ws + 0 * SZ;                    // overlays Q1t (dead after attn)
  short* On2 = ws + 1 * SZ;                    // overlays K1t
  short* Wc1 = ws + 12 * SZ + 442368;          // after Lpart
  short* Wc2 = Wc1 + 768 * 256;
  short* Wo1b = Wc2 + 768 * 512;
  short* Wo2b = Wo1b + 256 * 256;

  // A+B fused: X transpose-convert + weight conversions in one launch
  CvtArgs CA;
  CA.X1 = m1; CA.X2 = m2; CA.X1t = X1t; CA.X2t = X2t;
  CA.wsrc[0] = (const float*)d_in[2];  CA.wdst[0] = Wc1;          CA.wnelem[0] = 65536;  CA.wscale[0] = (float)QSCALE;
  CA.wsrc[1] = (const float*)d_in[4];  CA.wdst[1] = Wc1 + 65536;  CA.wnelem[1] = 65536;  CA.wscale[1] = 1.f;
  CA.wsrc[2] = (const float*)d_in[6];  CA.wdst[2] = Wc1 + 131072; CA.wnelem[2] = 65536;  CA.wscale[2] = 1.f;
  CA.wsrc[3] = (const float*)d_in[8];  CA.wdst[3] = Wc2;          CA.wnelem[3] = 131072; CA.wscale[3] = (float)QSCALE;
  CA.wsrc[4] = (const float*)d_in[10]; CA.wdst[4] = Wc2 + 131072; CA.wnelem[4] = 131072; CA.wscale[4] = 1.f;
  CA.wsrc[5] = (const float*)d_in[12]; CA.wdst[5] = Wc2 + 262144; CA.wnelem[5] = 131072; CA.wscale[5] = 1.f;
  CA.wsrc[6] = (const float*)d_in[14]; CA.wdst[6] = Wo1b;         CA.wnelem[6] = 65536;  CA.wscale[6] = 1.f;
  CA.wsrc[7] = (const float*)d_in[16]; CA.wdst[7] = Wo2b;         CA.wnelem[7] = 65536;  CA.wscale[7] = 1.f;
  hipLaunchKernelGGL(convert_all, dim3(128, 32), dim3(256), 0, stream, CA);

  // C: QKV projection GEMM
  hipLaunchKernelGGL(proj_gemm, dim3(18, 12, 4), dim3(256), 0, stream,
                     Wc1, Wc2, X1t, X2t,
                     (const float*)d_in[3], (const float*)d_in[5], (const float*)d_in[7],
                     (const float*)d_in[9], (const float*)d_in[11], (const float*)d_in[13],
                     Q1t, K1t, V1, Q2t, K2t, V2);

  // D: attention (3-way K-split; 128 queries/block; permuted-K staging)
  hipLaunchKernelGGL(attn_kernel, dim3(1728), dim3(256), 0, stream,
                     Q1t, K1t, V1, Q2t, K2t, V2, Opart, Lpart);

  // D2: merge + normalize + transpose
  hipLaunchKernelGGL(merge_kernel, dim3(36, 32), dim3(256), 0, stream,
                     Opart, Lpart, On1, On2);

  // E: output projection GEMM
  hipLaunchKernelGGL(outproj_kernel, dim3(18, 4, 4), dim3(256), 0, stream,
                     Wo1b, Wo2b, (const float*)d_in[15], (const float*)d_in[17],
                     On1, On2, (float*)d_out);
}